// Round 16
// baseline (254.661 us; speedup 1.0000x reference)
//
#include <hip/hip_runtime.h>

// Dynamics compressor: audio_db = 20*log10(|a|+1e-5);
// grd = max((thr-db)*(1-1/ratio), 0);
// g[t] = g[t-1] + (1-coeff)*(grd[t]-g[t-1]), coeff = att if grd>g else rel;
// out = a * 10^(-g/20)
//
// Chunked-parallel via contraction: |dg'/dg| = coeff <= 0.1, so a W=12
// warm-up from g=0 makes per-lane chunks exact to f32.
//
// R19 == R10 resubmit (R10..R18 all died to GPU-acquisition timeouts;
// the broker fails before the kernel is compiled/pushed).
// R10: persistent-wave software pipeline, zero LDS.
// R5 (barriered) = 79.7 us, R6 (barrier-free) = 81.5 us: identical ~80 us
// across different sync structures; occ ~57%, VALU ~34%, HBM ~31%, neither
// pipe saturated. Counter arithmetic: ~4.7 blocks/CU resident over 32
// rounds -> block lifetime ~29K cycles vs ~2K cycles of actual work. Waves
// issue one 4KB load burst then stall on vmcnt; no intra-wave ILP, TLP
// can't cover. Fix:
//  1. Each wave owns TPW=4 consecutive 1024-sample tiles and prefetches
//     tile t+1's loads while computing tile t (latency hides in-wave).
//  2. Loads go straight to registers, lane-strided 64B (lane l owns its
//     16-sample chunk = one sector; 4-instr group covers a contiguous
//     4KB burst, all bytes consumed). No LDS, no barriers, no lgkmcnt.
//  3. Warm-up tail via 12 __shfl_up from lane l-1's registers.
//  4. Tile seams inside a wave chain EXACTLY: lane 0 of tile t+1 takes
//     lane 63's final g (__shfl(g,63)) - no warm-up approximation there.
// Recurrence form unchanged (R4): g' = max(att*g+(1-att)*grd,
// rel*g+(1-rel)*grd), exact vs the reference branch since rel > att.

constexpr int T   = 256;  // 4 waves per block
constexpr int C   = 16;   // samples per lane per tile (one 64B sector)
constexpr int TPW = 4;    // tiles per wave (even -> ping-pong unroll)
constexpr int LT  = 64 * C;        // 1024 samples per wave-tile
constexpr int SPAN = LT * TPW;     // 4096 samples per wave
constexpr int W   = 12;   // warm-up lookback (contraction 1e-12)

__device__ __forceinline__ float get(const float4 (&x)[4], int i) {
    const float4 v = x[i >> 2];
    switch (i & 3) { case 0: return v.x; case 1: return v.y;
                     case 2: return v.z; default: return v.w; }
}

__global__ __launch_bounds__(T) void compressor_kernel(
    const float* __restrict__ audio,
    const float* __restrict__ thr_p,
    const float* __restrict__ ratio_p,
    const float* __restrict__ att_p,
    const float* __restrict__ rel_p,
    float* __restrict__ out)
{
    const int lane = threadIdx.x & 63;
    const int wv   = threadIdx.x >> 6;
    const long long wbase = ((long long)blockIdx.x * 4 + wv) * SPAN;

    const float thr   = *thr_p;
    const float ratio = *ratio_p;
    const float att   = *att_p;
    const float rel   = *rel_p;
    const float sfac  = 1.0f - 1.0f / ratio;
    const float GA    = thr * sfac;                     // grd = max(GB2*log2(y)+GA, 0)
    const float GB2   = -20.0f * sfac * 0.30102999566f; // log10(y)=log2(y)*log10(2)
    const float KEXP  = -0.05f * 3.32192809489f;        // 10^(-g/20) = 2^(KEXP*g)
    const float oatt  = 1.0f - att;
    const float orel  = 1.0f - rel;

    const bool has_hist = (wbase > 0);

    // Lane 0's first-tile history (12 samples before wbase). Issued before
    // the tile-0 load so its latency hides under it. wbase-12 is 16B-aligned.
    float hist[W];
#pragma unroll
    for (int i = 0; i < W; ++i) hist[i] = 0.0f;
    if (lane == 0 && has_hist) {
        const float4* hp = reinterpret_cast<const float4*>(audio + wbase - W);
        const float4 h0 = hp[0], h1 = hp[1], h2 = hp[2];
        hist[0]=h0.x; hist[1]=h0.y; hist[2] =h0.z; hist[3] =h0.w;
        hist[4]=h1.x; hist[5]=h1.y; hist[6] =h1.z; hist[7] =h1.w;
        hist[8]=h2.x; hist[9]=h2.y; hist[10]=h2.z; hist[11]=h2.w;
    }

    // Lane-strided tile load: lane l reads its own 64B sector via 4 float4.
    auto LOAD = [&](float4 (&x)[4], int t) {
        const float4* q = reinterpret_cast<const float4*>(audio + wbase
                            + (long long)t * LT) + lane * 4;
        x[0] = q[0]; x[1] = q[1]; x[2] = q[2]; x[3] = q[3];
    };

    float gcarry = 0.0f;

    // Process one tile held in registers; returns lane63's final g.
    auto PROC = [&](const float4 (&X)[4], int t, bool first) -> float {
        // Warm-up inputs: lane l gets lane l-1's last 12 samples (X[4..15]).
        float xw[W];
#pragma unroll
        for (int i = 0; i < W; ++i)
            xw[i] = __shfl_up(get(X, C - W + i), 1);
        if (lane == 0 && first && has_hist) {
#pragma unroll
            for (int i = 0; i < W; ++i) xw[i] = hist[i];
        }

        // Stage A: all grd (independent -> log2 pipelines).
        float gw[W], gm[C];
#pragma unroll
        for (int i = 0; i < W; ++i)
            gw[i] = fmaxf(fmaf(GB2, __log2f(fabsf(xw[i]) + 1e-5f), GA), 0.0f);
#pragma unroll
        for (int j = 0; j < C; ++j)
            gm[j] = fmaxf(fmaf(GB2, __log2f(fabsf(get(X, j)) + 1e-5f), GA), 0.0f);

        // Stage B: warm-up recurrence (lanes>=1 and lane0-first-with-hist).
        float g = 0.0f;
#pragma unroll
        for (int i = 0; i < W; ++i) {
            const float ga = fmaf(att, g, oatt * gw[i]);
            const float gr = fmaf(rel, g, orel * gw[i]);
            g = fmaxf(ga, gr);
        }
        if (lane == 0) g = first ? (has_hist ? g : 0.0f) : gcarry;

        // Main recurrence: chain = {fma || fma} -> max.
#pragma unroll
        for (int j = 0; j < C; ++j) {
            const float ga = fmaf(att, g, oatt * gm[j]);
            const float gr = fmaf(rel, g, orel * gm[j]);
            g = fmaxf(ga, gr);
            gm[j] = g; // smoothed gain
        }

        // Stage C + store (lane-strided 64B, sectors fully written).
        float4* q = reinterpret_cast<float4*>(out + wbase
                       + (long long)t * LT) + lane * 4;
#pragma unroll
        for (int k = 0; k < 4; ++k) {
            float4 o;
            o.x = get(X, 4*k+0) * __builtin_amdgcn_exp2f(KEXP * gm[4*k+0]);
            o.y = get(X, 4*k+1) * __builtin_amdgcn_exp2f(KEXP * gm[4*k+1]);
            o.z = get(X, 4*k+2) * __builtin_amdgcn_exp2f(KEXP * gm[4*k+2]);
            o.w = get(X, 4*k+3) * __builtin_amdgcn_exp2f(KEXP * gm[4*k+3]);
            q[k] = o;
        }
        return __shfl(g, 63); // exact seed for next tile's lane 0
    };

    // Ping-pong pipeline: compute tile t while tile t+1's loads fly.
    float4 xa[4], xb[4];
    LOAD(xa, 0);
    LOAD(xb, 1);
    gcarry = PROC(xa, 0, true);
    LOAD(xa, 2);
    gcarry = PROC(xb, 1, false);
    LOAD(xb, 3);
    gcarry = PROC(xa, 2, false);
    gcarry = PROC(xb, 3, false);
}

extern "C" void kernel_launch(void* const* d_in, const int* in_sizes, int n_in,
                              void* d_out, int out_size, void* d_ws, size_t ws_size,
                              hipStream_t stream) {
    const float* audio = (const float*)d_in[0];
    // d_in[1] = sample_rate (int) — unused by the reference math
    const float* thr   = (const float*)d_in[2];
    const float* ratio = (const float*)d_in[3];
    const float* att   = (const float*)d_in[4];
    const float* rel   = (const float*)d_in[5];
    float* outp = (float*)d_out;

    const int n = in_sizes[0];        // 1<<25, divisible by T*C*TPW (16384)
    const int grid = n / (T * C * TPW); // 2048 blocks (8/CU)
    compressor_kernel<<<grid, T, 0, stream>>>(audio, thr, ratio, att, rel, outp);
}

// Round 17
// 247.221 us; speedup vs baseline: 1.0301x; 1.0301x over previous
//
#include <hip/hip_runtime.h>

// Dynamics compressor: audio_db = 20*log10(|a|+1e-5);
// grd = max((thr-db)*(1-1/ratio), 0);
// g[t] = g[t-1] + (1-coeff)*(grd[t]-g[t-1]), coeff = att if grd>g else rel;
// out = a * 10^(-g/20)
//
// R20: pipelined-LDS persistent blocks (union of R5 and R10's good halves).
// Evidence: R5 79.7us / R6 81.5us (coalesced+LDS, latency-exposed, VALU 33%);
// R10 92us (pipelined but lane-chunk global access: 64 distinct 64B lines
// per instr -> TA flood, 16B partial-line stores -> WRITE_SIZE +18%, VALU 19%).
// Conclusions: (a) coalescing is binding -> transpose via LDS (R5 machinery,
// conflicts negligible); (b) pipelining requires loads in flight ACROSS
// barriers -> __syncthreads() emits vmcnt(0) drain, so use raw s_barrier +
// lgkmcnt(0)-only waits (T3/T4); prefetch goes to REGISTERS (no cross-thread
// visibility needed -> no vmcnt drain needed at barriers).
//
// Per block: NT=8 tiles x 2048 samples, dbuf LDS 2x8KB. Iter t:
//   issue loads tile t+2 -> regs (T14 early-issue)
//   ds_read own chunk+warmup of tile t; stash tile tail (parity)
//   compute (log2 stage A, {fma||fma}->max recurrence, per-thread W=12 warmup)
//   soft_barrier B; write outputs in place + stage tile t+1 regs->LDS
//   soft_barrier C; coalesced readback + global store
// Loads are in flight ~1.5 iters (~ covers 900cy HBM latency).

constexpr int T    = 256;      // threads (4 waves)
constexpr int C    = 8;        // samples per thread per tile
constexpr int TILE = T * C;    // 2048 floats = 8 KiB
constexpr int NT   = 8;        // tiles per block (block span 16384)
constexpr int W    = 12;       // warm-up lookback (contraction 1e-12)

// XOR bank swizzle, bijective within each 32-float group (R5-proven:
// serial/out pattern lands 2 lanes/bank = free; stage pattern ~2-way).
__device__ __forceinline__ int sw(int li) {
    return (li & ~31) | ((li & 31) ^ ((li >> 5) & 31));
}

// Barrier WITHOUT vmcnt drain: own ds ops committed (lgkmcnt(0)), then
// s_barrier. Register prefetch loads stay in flight across it.
__device__ __forceinline__ void soft_barrier() {
    asm volatile("s_waitcnt lgkmcnt(0)" ::: "memory");
    __builtin_amdgcn_s_barrier();
    asm volatile("" ::: "memory");
}

__global__ __launch_bounds__(T) void compressor_kernel(
    const float* __restrict__ audio,
    const float* __restrict__ thr_p,
    const float* __restrict__ ratio_p,
    const float* __restrict__ att_p,
    const float* __restrict__ rel_p,
    float* __restrict__ out)
{
    __shared__ float buf[2][TILE];   // 16 KiB double buffer
    __shared__ float stash[2][W];    // tile-tail inputs, parity-buffered

    const int tid = threadIdx.x;
    const long long blk0 = (long long)blockIdx.x * (TILE * NT);

    const float thr   = *thr_p;
    const float ratio = *ratio_p;
    const float att   = *att_p;
    const float rel   = *rel_p;
    const float sfac  = 1.0f - 1.0f / ratio;
    const float GA    = thr * sfac;                     // grd = max(GB2*log2(y)+GA,0)
    const float GB2   = -20.0f * sfac * 0.30102999566f; // log10(y)=log2(y)*log10(2)
    const float KEXP  = -0.05f * 3.32192809489f;        // 10^(-g/20)=2^(KEXP*g)
    const float oatt  = 1.0f - att;
    const float orel  = 1.0f - rel;

    const float4* a4 = reinterpret_cast<const float4*>(audio + blk0);
    float4*       o4 = reinterpret_cast<float4*>(out + blk0);

    // Block-boundary history (prev block's tail) for t==0, threads 0..1.
    float4 hv0 = {0,0,0,0}, hv1 = {0,0,0,0}, hv2 = {0,0,0,0};
    if (tid < 2 && blockIdx.x > 0) {
        const float4* hp = reinterpret_cast<const float4*>(audio + blk0 - W);
        hv0 = hp[0]; hv1 = hp[1]; hv2 = hp[2]; // blk0 % 16384 == 0 -> aligned
    }

    // Prologue: tile 0 (staged now) + tile 1 (pf regs, consumed end of iter 0).
    float4 c0 = a4[tid],          c1 = a4[T + tid];
    float4 pfa = a4[2 * T + tid], pfb = a4[3 * T + tid];

    auto put4 = [&](int b, int li, const float4 v) {
        const int base = li & ~31, j0 = li & 31, key = (li >> 5) & 31;
        buf[b][base + ((j0 + 0) ^ key)] = v.x;
        buf[b][base + ((j0 + 1) ^ key)] = v.y;
        buf[b][base + ((j0 + 2) ^ key)] = v.z;
        buf[b][base + ((j0 + 3) ^ key)] = v.w;
    };
    auto get4 = [&](int b, int li) {
        const int base = li & ~31, j0 = li & 31, key = (li >> 5) & 31;
        float4 v;
        v.x = buf[b][base + ((j0 + 0) ^ key)];
        v.y = buf[b][base + ((j0 + 1) ^ key)];
        v.z = buf[b][base + ((j0 + 2) ^ key)];
        v.w = buf[b][base + ((j0 + 3) ^ key)];
        return v;
    };

    put4(0, tid * 4, c0);
    put4(0, 1024 + tid * 4, c1);
    soft_barrier();               // tile 0 ready; tile 1 loads still in flight

    float4 p2a = {0,0,0,0}, p2b = {0,0,0,0};

#pragma unroll
    for (int t = 0; t < NT; ++t) {
        const int p = t & 1;      // buf[p] holds tile t inputs

        // (1) issue tile t+2 loads early (latency hides under everything below)
        if (t + 2 < NT) {
            p2a = a4[(t + 2) * 2 * T + tid];
            p2b = a4[(t + 2) * 2 * T + T + tid];
        }

        // (2) own chunk inputs
        float x[C];
#pragma unroll
        for (int j = 0; j < C; ++j) x[j] = buf[p][sw(tid * C + j)];

        // warm-up inputs: words [tid*C-W, tid*C) of tile t
        float xw[W];
        if (t == 0) {
            if (tid == 0) {
                xw[0]=hv0.x; xw[1]=hv0.y; xw[2] =hv0.z; xw[3] =hv0.w;
                xw[4]=hv1.x; xw[5]=hv1.y; xw[6] =hv1.z; xw[7] =hv1.w;
                xw[8]=hv2.x; xw[9]=hv2.y; xw[10]=hv2.z; xw[11]=hv2.w;
            } else if (tid == 1) {
                xw[0]=hv2.x; xw[1]=hv2.y; xw[2]=hv2.z; xw[3]=hv2.w;
#pragma unroll
                for (int i = 4; i < W; ++i) xw[i] = buf[p][sw(i - 4)];
            } else {
#pragma unroll
                for (int i = 0; i < W; ++i)
                    xw[i] = buf[p][sw(tid * C - W + i)];
            }
        } else {
#pragma unroll
            for (int i = 0; i < W; ++i) {
                const int w = tid * C - W + i;       // < 0 only for tid 0,1
                const float* src = (w < 0) ? &stash[p][W + w]
                                           : &buf[p][sw(w)];
                xw[i] = *src;   // address-select -> single ds_read, in-bounds
            }
        }

        // stash tile t's last 12 INPUT words for iter t+1 (slot (t+1)&1)
        if (tid == T - 2) {
            stash[p ^ 1][0] = x[4]; stash[p ^ 1][1] = x[5];
            stash[p ^ 1][2] = x[6]; stash[p ^ 1][3] = x[7];
        } else if (tid == T - 1) {
            stash[p ^ 1][4]  = x[0]; stash[p ^ 1][5]  = x[1];
            stash[p ^ 1][6]  = x[2]; stash[p ^ 1][7]  = x[3];
            stash[p ^ 1][8]  = x[4]; stash[p ^ 1][9]  = x[5];
            stash[p ^ 1][10] = x[6]; stash[p ^ 1][11] = x[7];
        }

        // (3) stage A: independent grd (log2 pipelines)
        float gw[W], gm[C];
#pragma unroll
        for (int i = 0; i < W; ++i)
            gw[i] = fmaxf(fmaf(GB2, __log2f(fabsf(xw[i]) + 1e-5f), GA), 0.0f);
#pragma unroll
        for (int j = 0; j < C; ++j)
            gm[j] = fmaxf(fmaf(GB2, __log2f(fabsf(x[j]) + 1e-5f), GA), 0.0f);

        // stage B: recurrence, chain = {fma || fma} -> max (exact: rel>att)
        float g = 0.0f;
        if (t == 0 && blockIdx.x == 0 && tid < 2) {
            // stream start: skip samples before t=0 (exact, g starts at 0)
            const int istart = W - tid * C; // 12 (tid0) or 4 (tid1)
#pragma unroll
            for (int i = 0; i < W; ++i) {
                const float ga = fmaf(att, g, oatt * gw[i]);
                const float gr = fmaf(rel, g, orel * gw[i]);
                const float gn = fmaxf(ga, gr);
                g = (i >= istart) ? gn : g;
            }
        } else {
#pragma unroll
            for (int i = 0; i < W; ++i) {
                const float ga = fmaf(att, g, oatt * gw[i]);
                const float gr = fmaf(rel, g, orel * gw[i]);
                g = fmaxf(ga, gr);
            }
        }
#pragma unroll
        for (int j = 0; j < C; ++j) {
            const float ga = fmaf(att, g, oatt * gm[j]);
            const float gr = fmaf(rel, g, orel * gm[j]);
            g = fmaxf(ga, gr);
            gm[j] = g; // smoothed gain
        }

        soft_barrier();  // B: all input reads of buf[p] complete everywhere

        // (4) outputs in place over own chunk
#pragma unroll
        for (int j = 0; j < C; ++j)
            buf[p][sw(tid * C + j)] =
                x[j] * __builtin_amdgcn_exp2f(KEXP * gm[j]);

        // (5) stage tile t+1 regs->LDS (counted vmcnt wait; p2 stays in flight)
        if (t + 1 < NT) {
            put4(p ^ 1, tid * 4, pfa);
            put4(p ^ 1, 1024 + tid * 4, pfb);
        }

        soft_barrier();  // C: outputs + next tile visible

        // (6) coalesced readback + store (wave-contiguous 16B lanes)
        const float4 r0 = get4(p, tid * 4);
        const float4 r1 = get4(p, 1024 + tid * 4);
        o4[t * 2 * T + tid]     = r0;
        o4[t * 2 * T + T + tid] = r1;

        pfa = p2a; pfb = p2b;   // tile t+2 regs become next iter's pf
    }
}

extern "C" void kernel_launch(void* const* d_in, const int* in_sizes, int n_in,
                              void* d_out, int out_size, void* d_ws, size_t ws_size,
                              hipStream_t stream) {
    const float* audio = (const float*)d_in[0];
    // d_in[1] = sample_rate (int) — unused by the reference math
    const float* thr   = (const float*)d_in[2];
    const float* ratio = (const float*)d_in[3];
    const float* att   = (const float*)d_in[4];
    const float* rel   = (const float*)d_in[5];
    float* outp = (float*)d_out;

    const int n = in_sizes[0];            // 1<<25, divisible by TILE*NT (16384)
    const int grid = n / (TILE * NT);     // 2048 blocks
    compressor_kernel<<<grid, T, 0, stream>>>(audio, thr, ratio, att, rel, outp);
}

// Round 18
// 231.176 us; speedup vs baseline: 1.1016x; 1.0694x over previous
//
#include <hip/hip_runtime.h>

// Dynamics compressor: audio_db = 20*log10(|a|+1e-5);
// grd = max((thr-db)*(1-1/ratio), 0);
// g[t] = g[t-1] + (1-coeff)*(grd[t]-g[t-1]), coeff = att if grd>g else rel;
// out = a * 10^(-g/20)
//
// R21: zero-LDS, perfectly-coalesced C=4 chunks, shuffle warm-up.
// Scorecard: R5 simple-LDS 79.7 | R6 nobarrier-LDS 81.5 | R10 reg-pipeline
// scattered 92 | R20 LDS-pipeline 113.7. Lessons: (a) R10: coalescing is
// binding -- per-instruction access must complete whole 64B lines (its
// 64-line/instr pattern inflated WRITE +18%, starved VALU); (b) R5/R6/R20:
// the LDS transpose machinery itself costs ~27us VALU-issue (swizzle math,
// ds ops) and pipelining variants only add overhead (R20 regressed).
// Unexplored corner = zero-LDS AND coalesced: C=4 makes a thread's chunk
// exactly one float4 -> lane l loads base+16B*l: contiguous, 4 lanes/line,
// lines completed in ONE instruction, no transpose needed. Warm-up (W=12)
// comes from lanes l-1..l-3 via 12 __shfl_up (register-only); lanes 0-2 of
// each wave read 12 history floats from global (L2-hot, 3/64 lanes).
// No LDS, no barriers, short ~160-instr waves, ~40 VGPR -> 8 waves/SIMD;
// 32 waves/CU x 1KB in flight covers Little's law (9.2 KB/CU) for full BW.
// Cost accepted: warmup redundancy (12+4)/4 = 4x per sample -> ~21us of
// VALU+trans pipe time, still < 43us memory floor => memory-bound shape.
//
// Warmup exactness: contraction |dg'/dg| = coeff <= rel = 0.1 per step ->
// 12 steps from g=0 => state error <= max_grd * 1e-12 (~6e-11), far below
// tolerance (validated by R5/R6 passing with same W).
// Stream start (samples < 0): nfab = max(12 - s0, 0) prefix steps are
// skipped via per-lane select (keeps g; garbage xw/NaN gw discarded), so
// thread 0 runs its own chunk from exactly g=0 like the reference scan.
// Recurrence form (R4-proven): g' = max(att*g+(1-att)*grd,
// rel*g+(1-rel)*grd); ga-gr = (rel-att)*(grd-g), rel>att -> max picks
// attack iff grd>g, exactly the reference branch.

constexpr int T = 256;   // threads per block (4 waves)
constexpr int C = 4;     // samples per thread = one float4 (coalescing unit)
constexpr int W = 12;    // warm-up lookback (contraction 1e-12)

__global__ __launch_bounds__(T) void compressor_kernel(
    const float* __restrict__ audio,
    const float* __restrict__ thr_p,
    const float* __restrict__ ratio_p,
    const float* __restrict__ att_p,
    const float* __restrict__ rel_p,
    float* __restrict__ out)
{
    const long long gt = (long long)blockIdx.x * T + threadIdx.x;
    const long long s0 = gt * C;            // first sample of this thread
    const int lane = threadIdx.x & 63;

    const float thr   = *thr_p;
    const float ratio = *ratio_p;
    const float att   = *att_p;
    const float rel   = *rel_p;
    const float sfac  = 1.0f - 1.0f / ratio;
    const float GA    = thr * sfac;                     // grd = max(GB2*log2(y)+GA,0)
    const float GB2   = -20.0f * sfac * 0.30102999566f; // log10(y)=log2(y)*log10(2)
    const float KEXP  = -0.05f * 3.32192809489f;        // 10^(-g/20)=2^(KEXP*g)
    const float oatt  = 1.0f - att;
    const float orel  = 1.0f - rel;

    // Own chunk: ONE coalesced float4 (lane-contiguous 16B, 4 lanes/line).
    const float4 x = *reinterpret_cast<const float4*>(audio + s0);

    // Warm-up inputs [s0-12, s0) from lanes l-3, l-2, l-1 (register-only).
    float xw[W];
    xw[0]  = __shfl_up(x.x, 3); xw[1]  = __shfl_up(x.y, 3);
    xw[2]  = __shfl_up(x.z, 3); xw[3]  = __shfl_up(x.w, 3);
    xw[4]  = __shfl_up(x.x, 2); xw[5]  = __shfl_up(x.y, 2);
    xw[6]  = __shfl_up(x.z, 2); xw[7]  = __shfl_up(x.w, 2);
    xw[8]  = __shfl_up(x.x, 1); xw[9]  = __shfl_up(x.y, 1);
    xw[10] = __shfl_up(x.z, 1); xw[11] = __shfl_up(x.w, 1);

    // Lanes 0..2: history crosses the wave boundary -> read from global
    // (12 scalar loads, 3/64 lanes active, lines are L1/L2-hot: the
    // previous wave just streamed them). Predicated for stream start.
    if (lane < 3) {
#pragma unroll
        for (int i = 0; i < W; ++i) {
            const long long a = s0 - W + i;
            if (a >= 0) xw[i] = audio[a];
        }
    }
    // Number of fabricated (pre-stream) warm-up entries: 12,8,4 for
    // gt=0,1,2; else 0. Their recurrence steps are skipped via select.
    const int nfab = (s0 < W) ? (int)(W - s0) : 0;

    // Stage A (warm-up): independent grd -> log2 pipelines.
    float gw[W];
#pragma unroll
    for (int i = 0; i < W; ++i)
        gw[i] = fmaxf(fmaf(GB2, __log2f(fabsf(xw[i]) + 1e-5f), GA), 0.0f);

    // Stage B (warm-up): chain = {fma || fma} -> max, skip fabricated prefix.
    float g = 0.0f;
#pragma unroll
    for (int i = 0; i < W; ++i) {
        const float ga = fmaf(att, g, oatt * gw[i]);
        const float gr = fmaf(rel, g, orel * gw[i]);
        const float gn = fmaxf(ga, gr);
        g = (i >= nfab) ? gn : g;   // fabricated steps keep g (NaN discarded)
    }

    // Own 4 samples: grd, recurrence, gain, store (coalesced float4).
    float xm[C] = {x.x, x.y, x.z, x.w};
    float gm[C];
#pragma unroll
    for (int j = 0; j < C; ++j)
        gm[j] = fmaxf(fmaf(GB2, __log2f(fabsf(xm[j]) + 1e-5f), GA), 0.0f);
#pragma unroll
    for (int j = 0; j < C; ++j) {
        const float ga = fmaf(att, g, oatt * gm[j]);
        const float gr = fmaf(rel, g, orel * gm[j]);
        g = fmaxf(ga, gr);
        gm[j] = g;                  // smoothed gain
    }

    float4 o;
    o.x = xm[0] * __builtin_amdgcn_exp2f(KEXP * gm[0]);
    o.y = xm[1] * __builtin_amdgcn_exp2f(KEXP * gm[1]);
    o.z = xm[2] * __builtin_amdgcn_exp2f(KEXP * gm[2]);
    o.w = xm[3] * __builtin_amdgcn_exp2f(KEXP * gm[3]);
    *reinterpret_cast<float4*>(out + s0) = o;
}

extern "C" void kernel_launch(void* const* d_in, const int* in_sizes, int n_in,
                              void* d_out, int out_size, void* d_ws, size_t ws_size,
                              hipStream_t stream) {
    const float* audio = (const float*)d_in[0];
    // d_in[1] = sample_rate (int) — unused by the reference math
    const float* thr   = (const float*)d_in[2];
    const float* ratio = (const float*)d_in[3];
    const float* att   = (const float*)d_in[4];
    const float* rel   = (const float*)d_in[5];
    float* outp = (float*)d_out;

    const int n = in_sizes[0];      // 1<<25, divisible by T*C (1024)
    const int grid = n / (T * C);   // 32768 blocks
    compressor_kernel<<<grid, T, 0, stream>>>(audio, thr, ratio, att, rel, outp);
}